// Round 6
// baseline (105.468 us; speedup 1.0000x reference)
//
#include <hip/hip_runtime.h>
#include <hip/hip_bf16.h>

#define NVID 256
#define DIM 1024

typedef short bf16x8 __attribute__((ext_vector_type(8)));
typedef float f32x4 __attribute__((ext_vector_type(4)));

__device__ inline void acc4(float4& a, const float4& v) {
    a.x += v.x; a.y += v.y; a.z += v.z; a.w += v.w;
}

__device__ inline unsigned short f2bf(float f) {
    __hip_bfloat16 h = __float2bfloat16(f);   // RNE
    unsigned short u;
    __builtin_memcpy(&u, &h, 2);
    return u;
}

__device__ inline float bf2f(unsigned short u) {
    return __uint_as_float(((unsigned)u) << 16);
}

// Agent-scope spin: poison is 0xAAAAAAAA, "done" is 1 — no flag init needed.
__device__ inline void wait_flag(int* f) {
    while (__hip_atomic_load(f, __ATOMIC_ACQUIRE, __HIP_MEMORY_SCOPE_AGENT) != 1)
        __builtin_amdgcn_s_sleep(1);
}

// 8-deep unrolled segmented row-mean (n >= 8 guaranteed: 8+(i%17)).
__device__ inline float4 mean_rows(const float* __restrict__ src, int off, int n, int t) {
    const float4* srcv = (const float4*)src + (size_t)off * (DIM / 4) + t;
    float4 a0 = {0,0,0,0}, a1 = {0,0,0,0}, a2 = {0,0,0,0}, a3 = {0,0,0,0};
    int r = 0;
    for (; r + 8 <= n; r += 8) {
        float4 v0 = srcv[(size_t)(r + 0) * (DIM / 4)];
        float4 v1 = srcv[(size_t)(r + 1) * (DIM / 4)];
        float4 v2 = srcv[(size_t)(r + 2) * (DIM / 4)];
        float4 v3 = srcv[(size_t)(r + 3) * (DIM / 4)];
        float4 v4 = srcv[(size_t)(r + 4) * (DIM / 4)];
        float4 v5 = srcv[(size_t)(r + 5) * (DIM / 4)];
        float4 v6 = srcv[(size_t)(r + 6) * (DIM / 4)];
        float4 v7 = srcv[(size_t)(r + 7) * (DIM / 4)];
        acc4(a0, v0); acc4(a1, v1); acc4(a2, v2); acc4(a3, v3);
        acc4(a0, v4); acc4(a1, v5); acc4(a2, v6); acc4(a3, v7);
    }
    for (; r < n; ++r) acc4(a0, srcv[(size_t)r * (DIM / 4)]);
    acc4(a0, a1); acc4(a2, a3); acc4(a0, a2);
    const float inv = 1.0f / (float)n;
    a0.x *= inv; a0.y *= inv; a0.z *= inv; a0.w *= inv;
    return a0;
}

// ---------------------------------------------------------------------------
// Single fused kernel, 256 blocks x 256 threads.
// Phase 1 (block v): clip-mean A[v] + cap-mean B[v] (bf16) + diag[v],
//   then device-scope release flag[v]=1. Block 0 also zeroes out[0] and
//   releases flag[NVID] ("out zeroed").
// Phase 2 (wave 0 of block b): hinge tile (b>>4, b&15) of S = A@B^T via
//   mfma_f32_16x16x32_bf16, gated by acquire-spin on the 32 row/col flags
//   + flag[NVID]. Tiles overlap with still-running producers; no 2nd
//   dispatch, no grid-wide barrier. Deadlock-free: production precedes
//   consumption per block and all 256 blocks are co-resident.
// ---------------------------------------------------------------------------
__global__ __launch_bounds__(256) void fused_loss_kernel(
    const float* __restrict__ im, const float* __restrict__ s,
    const int* __restrict__ num_clips, const int* __restrict__ num_caps,
    unsigned short* __restrict__ Ab, unsigned short* __restrict__ Bb,
    float* __restrict__ diag, int* __restrict__ flag,
    float* __restrict__ out)
{
    const int vid = blockIdx.x;
    const int t = threadIdx.x;
    const int wave = t >> 6, lane = t & 63;

    if (vid == 0 && t == 0) {
        __hip_atomic_store(out, 0.0f, __ATOMIC_RELAXED, __HIP_MEMORY_SCOPE_AGENT);
        __threadfence();
        __hip_atomic_store(&flag[NVID], 1, __ATOMIC_RELEASE, __HIP_MEMORY_SCOPE_AGENT);
    }

    // ---- phase 1: offsets via packed masked reduction (no serial loop) ----
    int val = num_clips[t] | (num_caps[t] << 16);
    int psum = (t < vid) ? val : 0;
    for (int o = 32; o > 0; o >>= 1) psum += __shfl_down(psum, o, 64);
    __shared__ int wpart[4];
    if (lane == 0) wpart[wave] = psum;
    __syncthreads();
    const int packed = wpart[0] + wpart[1] + wpart[2] + wpart[3];
    const int offc = packed & 0xFFFF;
    const int offp = (packed >> 16) & 0xFFFF;
    const int nc = num_clips[vid];
    const int np = num_caps[vid];

    float4 am = mean_rows(im, offc, nc, t);
    float4 bm = mean_rows(s,  offp, np, t);

    ushort4 ua, ub;
    ua.x = f2bf(am.x); ua.y = f2bf(am.y); ua.z = f2bf(am.z); ua.w = f2bf(am.w);
    ub.x = f2bf(bm.x); ub.y = f2bf(bm.y); ub.z = f2bf(bm.z); ub.w = f2bf(bm.w);
    ((ushort4*)(Ab + (size_t)vid * DIM))[t] = ua;
    ((ushort4*)(Bb + (size_t)vid * DIM))[t] = ub;

    float p = bf2f(ua.x) * bf2f(ub.x) + bf2f(ua.y) * bf2f(ub.y)
            + bf2f(ua.z) * bf2f(ub.z) + bf2f(ua.w) * bf2f(ub.w);
    for (int o = 32; o > 0; o >>= 1) p += __shfl_down(p, o, 64);
    __shared__ float wsum[4];
    if (lane == 0) wsum[wave] = p;
    __syncthreads();   // also drains all waves' Ab/Bb global stores (vmcnt 0)
    if (t == 0) {
        diag[vid] = wsum[0] + wsum[1] + wsum[2] + wsum[3];
        __threadfence();   // agent-scope: writeback so consumers on other XCDs see data
        __hip_atomic_store(&flag[vid], 1, __ATOMIC_RELEASE, __HIP_MEMORY_SCOPE_AGENT);
    }

    // ---- phase 2: wave 0 only, tile (vid>>4, vid&15) ----
    if (t >= 64) return;
    const int i0 = (vid >> 4) * 16, j0 = (vid & 15) * 16;

    if (t < 16)       wait_flag(&flag[i0 + t]);
    else if (t < 32)  wait_flag(&flag[j0 + t - 16]);
    else if (t == 32) wait_flag(&flag[NVID]);
    // wave-internal reconvergence; acquire loads above invalidated L1/L2-stale

    const int m = lane & 15, q = lane >> 4;
    const unsigned short* Ap = Ab + (size_t)(i0 + m) * DIM + q * 8;
    const unsigned short* Bp = Bb + (size_t)(j0 + m) * DIM + q * 8;

    f32x4 acc = {0.f, 0.f, 0.f, 0.f};
#pragma unroll
    for (int kb = 0; kb < DIM; kb += 32) {
        bf16x8 a = *(const bf16x8*)(Ap + kb);
        bf16x8 b = *(const bf16x8*)(Bp + kb);
        acc = __builtin_amdgcn_mfma_f32_16x16x32_bf16(a, b, acc, 0, 0, 0);
    }

    const int j = j0 + m;
    const float dj = diag[j];
    const float4 di = *(const float4*)&diag[i0 + q * 4];
    const float dia[4] = {di.x, di.y, di.z, di.w};

    float v = 0.f;
#pragma unroll
    for (int r = 0; r < 4; ++r) {
        const int i = i0 + q * 4 + r;
        if (i != j) {
            const float sv = acc[r];
            v += fmaxf(sv - dia[r], 0.f) + fmaxf(sv - dj, 0.f);
        }
    }

    for (int o = 32; o > 0; o >>= 1) v += __shfl_down(v, o, 64);
    if (lane == 0) atomicAdd(out, v);
}

// ---------------------------------------------------------------------------
extern "C" void kernel_launch(void* const* d_in, const int* in_sizes, int n_in,
                              void* d_out, int out_size, void* d_ws, size_t ws_size,
                              hipStream_t stream) {
    const float* im    = (const float*)d_in[0];
    const float* s     = (const float*)d_in[1];
    const int*   nclip = (const int*)d_in[2];
    const int*   ncap  = (const int*)d_in[3];
    float* out = (float*)d_out;

    unsigned short* Ab = (unsigned short*)d_ws;       // 512 KB
    unsigned short* Bb = Ab + NVID * DIM;             // 512 KB
    float* diag = (float*)(Bb + NVID * DIM);          // 1 KB
    int* flag = (int*)(diag + NVID);                  // 257 ints (poison!=1 ok)

    fused_loss_kernel<<<NVID, 256, 0, stream>>>(im, s, nclip, ncap, Ab, Bb, diag, flag, out);
}

// Round 7
// 86.727 us; speedup vs baseline: 1.2161x; 1.2161x over previous
//
#include <hip/hip_runtime.h>
#include <hip/hip_bf16.h>

#define NVID 256
#define DIM 1024

typedef short bf16x8 __attribute__((ext_vector_type(8)));
typedef float f32x4 __attribute__((ext_vector_type(4)));

__device__ inline void acc4(float4& a, const float4& v) {
    a.x += v.x; a.y += v.y; a.z += v.z; a.w += v.w;
}

__device__ inline unsigned short f2bf(float f) {
    __hip_bfloat16 h = __float2bfloat16(f);   // RNE
    unsigned short u;
    __builtin_memcpy(&u, &h, 2);
    return u;
}

__device__ inline float bf2f(unsigned short u) {
    return __uint_as_float(((unsigned)u) << 16);
}

// 8-deep unrolled segmented row-mean (n >= 8 guaranteed: 8+(i%17)).
// 8 outstanding float4 loads/thread -> 4 waves x 64 x 8 x 16B = 32 KB/CU
// in flight; x256 CU = 8 MB > 5.7 MB BDP -> BW-saturating.
__device__ inline float4 mean_rows(const float* __restrict__ src, int off, int n, int t) {
    const float4* srcv = (const float4*)src + (size_t)off * (DIM / 4) + t;
    float4 a0 = {0,0,0,0}, a1 = {0,0,0,0}, a2 = {0,0,0,0}, a3 = {0,0,0,0};
    int r = 0;
    for (; r + 8 <= n; r += 8) {
        float4 v0 = srcv[(size_t)(r + 0) * (DIM / 4)];
        float4 v1 = srcv[(size_t)(r + 1) * (DIM / 4)];
        float4 v2 = srcv[(size_t)(r + 2) * (DIM / 4)];
        float4 v3 = srcv[(size_t)(r + 3) * (DIM / 4)];
        float4 v4 = srcv[(size_t)(r + 4) * (DIM / 4)];
        float4 v5 = srcv[(size_t)(r + 5) * (DIM / 4)];
        float4 v6 = srcv[(size_t)(r + 6) * (DIM / 4)];
        float4 v7 = srcv[(size_t)(r + 7) * (DIM / 4)];
        acc4(a0, v0); acc4(a1, v1); acc4(a2, v2); acc4(a3, v3);
        acc4(a0, v4); acc4(a1, v5); acc4(a2, v6); acc4(a3, v7);
    }
    for (; r < n; ++r) acc4(a0, srcv[(size_t)r * (DIM / 4)]);
    acc4(a0, a1); acc4(a2, a3); acc4(a0, a2);
    const float inv = 1.0f / (float)n;
    a0.x *= inv; a0.y *= inv; a0.z *= inv; a0.w *= inv;
    return a0;
}

// ---------------------------------------------------------------------------
// K1: block i computes clip-mean A[i] AND cap-mean B[i] (bf16 out), plus
// diag[i] = A[i].B[i] in-register. Segment offsets via packed wave-shuffle
// reduction (nclip | ncap<<16, sums < 2^16 so no carry) — O(log) instead of
// the O(i) serial LDS loop. Zeroes d_out for K3's atomicAdd.
// NOTE (R6 lesson): do NOT fuse K3 in via agent-scope acquire spin-waits —
// each acquire invalidates per-XCD L1/L2 and thrashed the whole chip
// (fused kernel measured 44 µs vs ~8 µs for this two-kernel path).
// ---------------------------------------------------------------------------
__global__ __launch_bounds__(256) void mean_diag_kernel(
    const float* __restrict__ im, const float* __restrict__ s,
    const int* __restrict__ num_clips, const int* __restrict__ num_caps,
    unsigned short* __restrict__ Ab, unsigned short* __restrict__ Bb,
    float* __restrict__ diag, float* __restrict__ out)
{
    const int vid = blockIdx.x;
    const int t = threadIdx.x;
    const int wave = t >> 6, lane = t & 63;
    if (vid == 0 && t == 0) out[0] = 0.0f;

    // packed masked offset reduction: sum_{k<vid} (nclip[k] | ncap[k]<<16)
    int val = num_clips[t] | (num_caps[t] << 16);
    int psum = (t < vid) ? val : 0;
    for (int o = 32; o > 0; o >>= 1) psum += __shfl_down(psum, o, 64);
    __shared__ int wpart[4];
    if (lane == 0) wpart[wave] = psum;
    __syncthreads();
    const int packed = wpart[0] + wpart[1] + wpart[2] + wpart[3];
    const int offc = packed & 0xFFFF;
    const int offp = (packed >> 16) & 0xFFFF;
    const int nc = num_clips[vid];
    const int np = num_caps[vid];

    float4 am = mean_rows(im, offc, nc, t);
    float4 bm = mean_rows(s,  offp, np, t);

    ushort4 ua, ub;
    ua.x = f2bf(am.x); ua.y = f2bf(am.y); ua.z = f2bf(am.z); ua.w = f2bf(am.w);
    ub.x = f2bf(bm.x); ub.y = f2bf(bm.y); ub.z = f2bf(bm.z); ub.w = f2bf(bm.w);
    ((ushort4*)(Ab + (size_t)vid * DIM))[t] = ua;
    ((ushort4*)(Bb + (size_t)vid * DIM))[t] = ub;

    // diag from bf16-rounded values (consistent with K3's bf16 GEMM)
    float p = bf2f(ua.x) * bf2f(ub.x) + bf2f(ua.y) * bf2f(ub.y)
            + bf2f(ua.z) * bf2f(ub.z) + bf2f(ua.w) * bf2f(ub.w);
    for (int o = 32; o > 0; o >>= 1) p += __shfl_down(p, o, 64);
    __shared__ float wsum[4];
    if (lane == 0) wsum[wave] = p;
    __syncthreads();
    if (t == 0) diag[vid] = wsum[0] + wsum[1] + wsum[2] + wsum[3];
}

// ---------------------------------------------------------------------------
// K3: S = A @ B^T via mfma_f32_16x16x32_bf16, fused hinge + reduce.
// One wave per 16x16 tile; grid 16x16. Fragments straight from global
// (A,B bf16 = 1 MB total -> L2-resident; 16 B/lane contiguous).
//   A-frag: A[i0 + (lane&15)][kb + (lane>>4)*8 + j]
//   B-frag: B[j0 + (lane&15)][kb + (lane>>4)*8 + j]
//   C/D:    S[i0 + (lane>>4)*4 + r][j0 + (lane&15)]   (m89/m91 layout)
// ---------------------------------------------------------------------------
__global__ __launch_bounds__(64) void loss_kernel(
    const unsigned short* __restrict__ Ab, const unsigned short* __restrict__ Bb,
    const float* __restrict__ diag, float* __restrict__ out)
{
    const int lane = threadIdx.x;
    const int i0 = blockIdx.y * 16, j0 = blockIdx.x * 16;
    const int m = lane & 15, q = lane >> 4;

    const unsigned short* Ap = Ab + (size_t)(i0 + m) * DIM + q * 8;
    const unsigned short* Bp = Bb + (size_t)(j0 + m) * DIM + q * 8;

    f32x4 acc = {0.f, 0.f, 0.f, 0.f};
#pragma unroll
    for (int kb = 0; kb < DIM; kb += 32) {
        bf16x8 a = *(const bf16x8*)(Ap + kb);
        bf16x8 b = *(const bf16x8*)(Bp + kb);
        acc = __builtin_amdgcn_mfma_f32_16x16x32_bf16(a, b, acc, 0, 0, 0);
    }

    const int j = j0 + m;
    const float dj = diag[j];
    const float4 di = *(const float4*)&diag[i0 + q * 4];
    const float dia[4] = {di.x, di.y, di.z, di.w};

    float v = 0.f;
#pragma unroll
    for (int r = 0; r < 4; ++r) {
        const int i = i0 + q * 4 + r;
        if (i != j) {
            const float sv = acc[r];
            v += fmaxf(sv - dia[r], 0.f) + fmaxf(sv - dj, 0.f);
        }
    }

    for (int o = 32; o > 0; o >>= 1) v += __shfl_down(v, o, 64);
    if (lane == 0) atomicAdd(out, v);
}

// ---------------------------------------------------------------------------
extern "C" void kernel_launch(void* const* d_in, const int* in_sizes, int n_in,
                              void* d_out, int out_size, void* d_ws, size_t ws_size,
                              hipStream_t stream) {
    const float* im    = (const float*)d_in[0];
    const float* s     = (const float*)d_in[1];
    const int*   nclip = (const int*)d_in[2];
    const int*   ncap  = (const int*)d_in[3];
    float* out = (float*)d_out;

    unsigned short* Ab = (unsigned short*)d_ws;       // 512 KB
    unsigned short* Bb = Ab + NVID * DIM;             // 512 KB
    float* diag = (float*)(Bb + NVID * DIM);          // 1 KB

    mean_diag_kernel<<<NVID, 256, 0, stream>>>(im, s, nclip, ncap, Ab, Bb, diag, out);
    loss_kernel<<<dim3(16, 16), 64, 0, stream>>>(Ab, Bb, diag, out);
}